// Round 10
// baseline (172.339 us; speedup 1.0000x reference)
//
#include <hip/hip_runtime.h>
#include <math.h>

#define L_ 2
#define BAT_ 32
#define A_ 64
#define B_ 1024
#define D_ 128
#define NBITS_ 1024
#define NW 32                 // u32 words per code (1024 bits)
#define NQROWS (L_*BAT_*A_)   // 4096
#define NDROWS (L_*BAT_*B_)   // 65536
#define NROWS (NQROWS + NDROWS) // 69632

#define TM 128                // rows per block
#define TN 128                // bits per block
#define KH 32                 // K staged in quarters -> LDS 36.9 KB -> 4 blocks/CU
// LDS row: [hi 0..31 | lo 32..63 | pad 8] bf16 -> 72 elems = 36 dw.
// 36 ≡ 4 (mod 32): frag start banks 4*col -> 8 groups x 2 lanes = 2-way = free;
// 72 % 8 == 0 keeps 16-B alignment for ds_read_b128.
#define RS 72

typedef __bf16 bf16x4 __attribute__((ext_vector_type(4)));
typedef __bf16 bf16x8 __attribute__((ext_vector_type(8)));
typedef float  f32x4  __attribute__((ext_vector_type(4)));

// ---------------- Stage 1: LSH sign-hash (bf16-split MFMA + ballot pack) ----
// R9 structure with KH=32 for 4 blocks/CU occupancy (was 2: the ~50% stall
// fraction came from 2 waves/SIMD having nothing to cover barrier drains).
// NOTE: no min-waves launch_bounds — R6's (256,3) forced VGPR=84 and regressed.
__global__ __launch_bounds__(256) void hash_kernel(
    const float* __restrict__ qe, const float* __restrict__ de,
    const float* __restrict__ r, unsigned int* __restrict__ codes_t)
{
    __shared__ __align__(16) __bf16 As[TM * RS];   // 18432 B
    __shared__ __align__(16) __bf16 Bs[TN * RS];   // 18432 B (36864 total)

    const int t = threadIdx.x;
    const int row0 = blockIdx.x * TM;   // 4096 % 128 == 0: no q/d straddle
    const int bit0 = blockIdx.y * TN;

    const float* abase = (row0 < NQROWS) ? (qe + (size_t)row0 * D_)
                                         : (de + (size_t)(row0 - NQROWS) * D_);
    const float* bbase = r + (size_t)bit0 * D_;

    const int wv   = t >> 6;          // wave 0..3
    const int lane = t & 63;
    const int quad = lane >> 4;       // 0..3
    const int col  = lane & 15;       // 0..15
    const int wrow = (wv >> 1) * 64;  // wave's row offset in block tile
    const int wbit = (wv & 1) * 64;   // wave's bit offset in block tile

    f32x4 acc[4][4];
    #pragma unroll
    for (int ti = 0; ti < 4; ++ti)
        #pragma unroll
        for (int tj = 0; tj < 4; ++tj)
            acc[ti][tj] = (f32x4){0.f, 0.f, 0.f, 0.f};

    #pragma unroll
    for (int ks = 0; ks < D_; ks += KH) {
        if (ks) __syncthreads();
        // stage 128x32 fp32 slice of A and B, split into bf16 hi|lo in LDS
        #pragma unroll
        for (int i = 0; i < 4; ++i) {
            int f = (t + i * 256) * 4;      // flat idx in 128x32 tile
            int rr = f >> 5, cc = f & 31;
            float4 v = *(const float4*)(abase + (size_t)rr * D_ + ks + cc);
            bf16x4 hi, lo;
            hi[0] = (__bf16)v.x; hi[1] = (__bf16)v.y;
            hi[2] = (__bf16)v.z; hi[3] = (__bf16)v.w;
            lo[0] = (__bf16)(v.x - (float)hi[0]);
            lo[1] = (__bf16)(v.y - (float)hi[1]);
            lo[2] = (__bf16)(v.z - (float)hi[2]);
            lo[3] = (__bf16)(v.w - (float)hi[3]);
            *(bf16x4*)(&As[rr * RS + cc])      = hi;
            *(bf16x4*)(&As[rr * RS + 32 + cc]) = lo;
        }
        #pragma unroll
        for (int i = 0; i < 4; ++i) {
            int f = (t + i * 256) * 4;
            int rr = f >> 5, cc = f & 31;
            float4 v = *(const float4*)(bbase + (size_t)rr * D_ + ks + cc);
            bf16x4 hi, lo;
            hi[0] = (__bf16)v.x; hi[1] = (__bf16)v.y;
            hi[2] = (__bf16)v.z; hi[3] = (__bf16)v.w;
            lo[0] = (__bf16)(v.x - (float)hi[0]);
            lo[1] = (__bf16)(v.y - (float)hi[1]);
            lo[2] = (__bf16)(v.z - (float)hi[2]);
            lo[3] = (__bf16)(v.w - (float)hi[3]);
            *(bf16x4*)(&Bs[rr * RS + cc])      = hi;
            *(bf16x4*)(&Bs[rr * RS + 32 + cc]) = lo;
        }
        __syncthreads();

        // 3 segments: (A-off, B-off) = (hi,hi), (hi,lo), (lo,hi).
        // Identical LDS addresses across segments -> compiler CSEs the reloads.
        #pragma unroll
        for (int seg = 0; seg < 3; ++seg) {
            const int ao = (seg == 2) ? 32 : 0;
            const int bo = (seg == 1) ? 32 : 0;
            bf16x8 af[4], bfr[4];
            #pragma unroll
            for (int ti = 0; ti < 4; ++ti)
                af[ti] = *(const bf16x8*)(
                    &As[(wrow + ti * 16 + col) * RS + ao + quad * 8]);
            #pragma unroll
            for (int tj = 0; tj < 4; ++tj)
                bfr[tj] = *(const bf16x8*)(
                    &Bs[(wbit + tj * 16 + col) * RS + bo + quad * 8]);
            #pragma unroll
            for (int ti = 0; ti < 4; ++ti)
                #pragma unroll
                for (int tj = 0; tj < 4; ++tj)
                    acc[ti][tj] = __builtin_amdgcn_mfma_f32_16x16x32_bf16(
                        af[ti], bfr[tj], acc[ti][tj], 0, 0, 0);
        }
    }

    // Sign-pack via ballot; C/D layout (m89): col=lane&15, row=quad*4+reg.
    // TRANSPOSED store: codes_t[word][row].
    #pragma unroll
    for (int ti = 0; ti < 4; ++ti) {
        #pragma unroll
        for (int rg = 0; rg < 4; ++rg) {
            unsigned long long b[4];
            #pragma unroll
            for (int tj = 0; tj < 4; ++tj)
                b[tj] = __ballot(acc[ti][tj][rg] > 0.f);
            if (col < 2) {
                const int w = col;
                unsigned int lo16 = (unsigned int)(b[2 * w]     >> (16 * quad)) & 0xFFFFu;
                unsigned int hi16 = (unsigned int)(b[2 * w + 1] >> (16 * quad)) & 0xFFFFu;
                const int row = row0 + wrow + ti * 16 + quad * 4 + rg;
                const int wg  = blockIdx.y * 4 + (wv & 1) * 2 + w;
                codes_t[(size_t)wg * NROWS + row] = lo16 | (hi16 << 16);
            }
        }
    }
}

// ---------------- Stage 2: Hamming -> cos (HW v_cos) -> mask -> out ---------
// UNCHANGED from R9. grid: 2048 blocks, 8 blocks/CU = full wave occupancy.
__global__ __launch_bounds__(256) void simmat_kernel(
    const unsigned int* __restrict__ codes_t,
    const int* __restrict__ qtok, const int* __restrict__ dtok,
    float* __restrict__ out)
{
    __shared__ unsigned int qc[8 * 36];   // 8 a-rows, stride 36 (16B-aligned)

    const int blk  = blockIdx.x;
    const int ct   = blk & 3;
    const int asub = (blk >> 2) & 7;
    const int b    = (blk >> 5) & 31;
    const int l    = blk >> 10;
    const int t    = threadIdx.x;

    const int a0 = asub * 8;
    const int qrow0 = (l * BAT_ + b) * A_ + a0;
    // stage 8x32 query words: t -> (w = t>>3, a = t&7), coalesced in rows
    if (t < 256) {
        int w = t >> 3, a = t & 7;
        qc[a * 36 + w] = codes_t[(size_t)w * NROWS + qrow0 + a];
    }
    __syncthreads();

    const int c = ct * 256 + t;
    const size_t drow = (size_t)NQROWS + (size_t)(l * BAT_ + b) * B_ + c;
    unsigned int dc[NW];
    #pragma unroll
    for (int w = 0; w < NW; ++w) dc[w] = codes_t[(size_t)w * NROWS + drow];
    const float dm = (dtok[b * B_ + c] != 0) ? 1.f : 0.f;

    float* obase = out + ((size_t)((b * L_ + l) * A_ + a0)) * B_ + c;
    #pragma unroll
    for (int ai = 0; ai < 8; ++ai) {
        int ham = 0;
        #pragma unroll
        for (int m = 0; m < 8; ++m) {
            uint4 qv = *(const uint4*)(&qc[ai * 36 + m * 4]);  // uniform bcast
            ham += __popc(qv.x ^ dc[4 * m])     + __popc(qv.y ^ dc[4 * m + 1])
                 + __popc(qv.z ^ dc[4 * m + 2]) + __popc(qv.w ^ dc[4 * m + 3]);
        }
        const float qmv = (qtok[b * A_ + a0 + ai] != 0) ? 1.f : 0.f; // uniform
        float sim = __cosf((float)M_PI / (float)NBITS_ * (float)ham);
        obase[(size_t)ai * B_] = sim * (qmv * dm);
    }
}

extern "C" void kernel_launch(void* const* d_in, const int* in_sizes, int n_in,
                              void* d_out, int out_size, void* d_ws, size_t ws_size,
                              hipStream_t stream) {
    const float* qe  = (const float*)d_in[0];  // [L,BAT,A,D]
    const float* de  = (const float*)d_in[1];  // [L,BAT,B,D]
    const int* qtok  = (const int*)d_in[2];    // [BAT,A]
    const int* dtok  = (const int*)d_in[3];    // [BAT,B]
    const float* r   = (const float*)d_in[4];  // [NBITS,D]
    float* out = (float*)d_out;                // [BAT,L,A,B] fp32
    unsigned int* codes_t = (unsigned int*)d_ws; // [NW][NROWS] = 8.9 MB

    dim3 g1(NROWS / TM, NBITS_ / TN);
    hash_kernel<<<g1, 256, 0, stream>>>(qe, de, r, codes_t);
    simmat_kernel<<<L_ * BAT_ * 8 * 4, 256, 0, stream>>>(codes_t, qtok, dtok, out);
}

// Round 11
// 165.295 us; speedup vs baseline: 1.0426x; 1.0426x over previous
//
#include <hip/hip_runtime.h>
#include <math.h>

#define L_ 2
#define BAT_ 32
#define A_ 64
#define B_ 1024
#define D_ 128
#define NBITS_ 1024
#define NW 32                 // u32 words per code (1024 bits)
#define NQROWS (L_*BAT_*A_)   // 4096
#define NDROWS (L_*BAT_*B_)   // 65536
#define NROWS (NQROWS + NDROWS) // 69632

#define TM 128                // rows per block
#define TN 128                // bits per block
#define KH 64                 // K staged in halves (KH=32 measured worse, R10)
// LDS row per K-half: [hi 0..63 | lo 64..127 | pad 8] bf16 -> stride 136
#define RS 136

typedef __bf16 bf16x4 __attribute__((ext_vector_type(4)));
typedef __bf16 bf16x8 __attribute__((ext_vector_type(8)));
typedef float  f32x4  __attribute__((ext_vector_type(4)));

// ---- Stage 0: presplit qe|de|r into packed bf16 hi/lo rows ----------------
// Row layout (256 bf16): [h(0:64) | l(0:64) | h(64:128) | l(64:128)]
// so a K-half (ks=0 or 64) is one contiguous 128-bf16 run at offset ks*2.
__global__ __launch_bounds__(256) void presplit_kernel(
    const float* __restrict__ qe, const float* __restrict__ de,
    const float* __restrict__ r, __bf16* __restrict__ asp,
    __bf16* __restrict__ rsp)
{
    int tid = blockIdx.x * 256 + threadIdx.x;   // 70656 rows * 32 f4 = 2260992
    int row = tid >> 5;
    int c4  = (tid & 31) * 4;
    const float* src;
    __bf16* dst;
    if (row < NQROWS) {
        src = qe + (size_t)row * D_;            dst = asp + (size_t)row * 256;
    } else if (row < NROWS) {
        src = de + (size_t)(row - NQROWS) * D_; dst = asp + (size_t)row * 256;
    } else {
        src = r + (size_t)(row - NROWS) * D_;   dst = rsp + (size_t)(row - NROWS) * 256;
    }
    float4 v = *(const float4*)(src + c4);
    bf16x4 hi, lo;
    hi[0] = (__bf16)v.x; hi[1] = (__bf16)v.y;
    hi[2] = (__bf16)v.z; hi[3] = (__bf16)v.w;
    lo[0] = (__bf16)(v.x - (float)hi[0]);
    lo[1] = (__bf16)(v.y - (float)hi[1]);
    lo[2] = (__bf16)(v.z - (float)hi[2]);
    lo[3] = (__bf16)(v.w - (float)hi[3]);
    int pos = ((c4 & 64) ? 128 : 0) + (c4 & 63);
    *(bf16x4*)(dst + pos)      = hi;
    *(bf16x4*)(dst + pos + 64) = lo;
}

// ---- Stage 1: LSH sign-hash (bf16-split MFMA + ballot pack) ----------------
// R9 structure; staging is now a pure bf16x8 copy from presplit sources
// (zero conversion VALU in the K-loop). Frag loop / epilogue identical to R9.
__global__ __launch_bounds__(256) void hash_kernel(
    const __bf16* __restrict__ asp, const __bf16* __restrict__ rsp,
    unsigned int* __restrict__ codes_t)
{
    __shared__ __align__(16) __bf16 As[TM * RS];   // 34816 B
    __shared__ __align__(16) __bf16 Bs[TN * RS];   // 34816 B

    const int t = threadIdx.x;
    const int row0 = blockIdx.x * TM;
    const int bit0 = blockIdx.y * TN;

    const __bf16* abase = asp + (size_t)row0 * 256;
    const __bf16* bbase = rsp + (size_t)bit0 * 256;

    const int wv   = t >> 6;          // wave 0..3
    const int lane = t & 63;
    const int quad = lane >> 4;       // 0..3
    const int col  = lane & 15;       // 0..15
    const int wrow = (wv >> 1) * 64;
    const int wbit = (wv & 1) * 64;

    f32x4 acc[4][4];
    #pragma unroll
    for (int ti = 0; ti < 4; ++ti)
        #pragma unroll
        for (int tj = 0; tj < 4; ++tj)
            acc[ti][tj] = (f32x4){0.f, 0.f, 0.f, 0.f};

    #pragma unroll
    for (int ks = 0; ks < D_; ks += KH) {
        if (ks) __syncthreads();
        // stage 128x[hi64|lo64] bf16 copies: 8 x (b128 load + b128 LDS write)
        #pragma unroll
        for (int i = 0; i < 8; ++i) {
            int f = (t + i * 256) * 8;      // bf16 idx in 128x128 half-tile
            int rr = f >> 7, cc = f & 127;
            bf16x8 v = *(const bf16x8*)(abase + (size_t)rr * 256 + ks * 2 + cc);
            *(bf16x8*)(&As[rr * RS + cc]) = v;
        }
        #pragma unroll
        for (int i = 0; i < 8; ++i) {
            int f = (t + i * 256) * 8;
            int rr = f >> 7, cc = f & 127;
            bf16x8 v = *(const bf16x8*)(bbase + (size_t)rr * 256 + ks * 2 + cc);
            *(bf16x8*)(&Bs[rr * RS + cc]) = v;
        }
        __syncthreads();

        // 3 segments: (A-off, B-off) = (hi,hi), (hi,lo), (lo,hi)
        #pragma unroll
        for (int seg = 0; seg < 3; ++seg) {
            const int ao = (seg == 2) ? 64 : 0;
            const int bo = (seg == 1) ? 64 : 0;
            #pragma unroll
            for (int kk = 0; kk < KH; kk += 32) {
                bf16x8 af[4], bfr[4];
                #pragma unroll
                for (int ti = 0; ti < 4; ++ti)
                    af[ti] = *(const bf16x8*)(
                        &As[(wrow + ti * 16 + col) * RS + ao + kk + quad * 8]);
                #pragma unroll
                for (int tj = 0; tj < 4; ++tj)
                    bfr[tj] = *(const bf16x8*)(
                        &Bs[(wbit + tj * 16 + col) * RS + bo + kk + quad * 8]);
                #pragma unroll
                for (int ti = 0; ti < 4; ++ti)
                    #pragma unroll
                    for (int tj = 0; tj < 4; ++tj)
                        acc[ti][tj] = __builtin_amdgcn_mfma_f32_16x16x32_bf16(
                            af[ti], bfr[tj], acc[ti][tj], 0, 0, 0);
            }
        }
    }

    // Sign-pack via ballot; C/D layout (m89): col=lane&15, row=quad*4+reg.
    // TRANSPOSED store: codes_t[word][row].
    #pragma unroll
    for (int ti = 0; ti < 4; ++ti) {
        #pragma unroll
        for (int rg = 0; rg < 4; ++rg) {
            unsigned long long b[4];
            #pragma unroll
            for (int tj = 0; tj < 4; ++tj)
                b[tj] = __ballot(acc[ti][tj][rg] > 0.f);
            if (col < 2) {
                const int w = col;
                unsigned int lo16 = (unsigned int)(b[2 * w]     >> (16 * quad)) & 0xFFFFu;
                unsigned int hi16 = (unsigned int)(b[2 * w + 1] >> (16 * quad)) & 0xFFFFu;
                const int row = row0 + wrow + ti * 16 + quad * 4 + rg;
                const int wg  = blockIdx.y * 4 + (wv & 1) * 2 + w;
                codes_t[(size_t)wg * NROWS + row] = lo16 | (hi16 << 16);
            }
        }
    }
}

// ---- Stage 2: Hamming -> cos (HW v_cos) -> mask -> out ---------------------
// UNCHANGED from R9. grid: 2048 blocks, 8 blocks/CU.
__global__ __launch_bounds__(256) void simmat_kernel(
    const unsigned int* __restrict__ codes_t,
    const int* __restrict__ qtok, const int* __restrict__ dtok,
    float* __restrict__ out)
{
    __shared__ unsigned int qc[8 * 36];

    const int blk  = blockIdx.x;
    const int ct   = blk & 3;
    const int asub = (blk >> 2) & 7;
    const int b    = (blk >> 5) & 31;
    const int l    = blk >> 10;
    const int t    = threadIdx.x;

    const int a0 = asub * 8;
    const int qrow0 = (l * BAT_ + b) * A_ + a0;
    if (t < 256) {
        int w = t >> 3, a = t & 7;
        qc[a * 36 + w] = codes_t[(size_t)w * NROWS + qrow0 + a];
    }
    __syncthreads();

    const int c = ct * 256 + t;
    const size_t drow = (size_t)NQROWS + (size_t)(l * BAT_ + b) * B_ + c;
    unsigned int dc[NW];
    #pragma unroll
    for (int w = 0; w < NW; ++w) dc[w] = codes_t[(size_t)w * NROWS + drow];
    const float dm = (dtok[b * B_ + c] != 0) ? 1.f : 0.f;

    float* obase = out + ((size_t)((b * L_ + l) * A_ + a0)) * B_ + c;
    #pragma unroll
    for (int ai = 0; ai < 8; ++ai) {
        int ham = 0;
        #pragma unroll
        for (int m = 0; m < 8; ++m) {
            uint4 qv = *(const uint4*)(&qc[ai * 36 + m * 4]);
            ham += __popc(qv.x ^ dc[4 * m])     + __popc(qv.y ^ dc[4 * m + 1])
                 + __popc(qv.z ^ dc[4 * m + 2]) + __popc(qv.w ^ dc[4 * m + 3]);
        }
        const float qmv = (qtok[b * A_ + a0 + ai] != 0) ? 1.f : 0.f;
        float sim = __cosf((float)M_PI / (float)NBITS_ * (float)ham);
        obase[(size_t)ai * B_] = sim * (qmv * dm);
    }
}

extern "C" void kernel_launch(void* const* d_in, const int* in_sizes, int n_in,
                              void* d_out, int out_size, void* d_ws, size_t ws_size,
                              hipStream_t stream) {
    const float* qe  = (const float*)d_in[0];  // [L,BAT,A,D]
    const float* de  = (const float*)d_in[1];  // [L,BAT,B,D]
    const int* qtok  = (const int*)d_in[2];    // [BAT,A]
    const int* dtok  = (const int*)d_in[3];    // [BAT,B]
    const float* r   = (const float*)d_in[4];  // [NBITS,D]
    float* out = (float*)d_out;                // [BAT,L,A,B] fp32

    // ws: [0, 8.5MB) codes_t | [8.5, 9.0MB) rsp | [9.0MB, +34MB) asp
    unsigned int* codes_t = (unsigned int*)d_ws;                    // 8912896 B
    __bf16* rsp = (__bf16*)((char*)d_ws + 8912896);                 // 524288 B
    __bf16* asp = (__bf16*)((char*)d_ws + 8912896 + 524288);        // 35651584 B

    presplit_kernel<<<(70656 * 32) / 256, 256, 0, stream>>>(qe, de, r, asp, rsp);
    dim3 g1(NROWS / TM, NBITS_ / TN);
    hash_kernel<<<g1, 256, 0, stream>>>(asp, rsp, codes_t);
    simmat_kernel<<<L_ * BAT_ * 8 * 4, 256, 0, stream>>>(codes_t, qtok, dtok, out);
}

// Round 12
// 160.969 us; speedup vs baseline: 1.0706x; 1.0269x over previous
//
#include <hip/hip_runtime.h>
#include <math.h>

#define L_ 2
#define BAT_ 32
#define A_ 64
#define B_ 1024
#define D_ 128
#define NBITS_ 1024
#define NW 32                 // u32 words per code (1024 bits)
#define NQROWS (L_*BAT_*A_)   // 4096
#define NDROWS (L_*BAT_*B_)   // 65536
#define NROWS (NQROWS + NDROWS) // 69632
#define NAGRP (NROWS / 16)    // 4352 A-row groups of 16
#define NBGRP (NBITS_ / 16)   // 64 bit groups of 16

#define TM 128                // rows per block
#define TN 128                // bits per block

typedef __bf16 bf16x8 __attribute__((ext_vector_type(8)));
typedef float  f32x4  __attribute__((ext_vector_type(4)));

// ---- Stage 0: split fp32 -> bf16 hi/lo AND swizzle into MFMA fragment order.
// Per 16-row group: layout [cbi:8][quad:4][col:16][8 bf16] = 4096 bf16 (8 KB).
// Chunk index c = ks*16 + hl*8 + kk*4 + quad maps to source fp32
// k-offset ks*64 + kk*32 + quad*8 (hi if hl=0, lo if hl=1); cbi = c>>2.
// A wave's fragment load is then base + lane*16B: perfectly coalesced, and the
// hash kernel needs NO LDS and NO barriers at all.
__global__ __launch_bounds__(256) void preswz_kernel(
    const float* __restrict__ qe, const float* __restrict__ de,
    const float* __restrict__ r, __bf16* __restrict__ asw,
    __bf16* __restrict__ rsw)
{
    const int g = blockIdx.x;       // 0..4415: A groups then r groups
    const int t = threadIdx.x;
    const int ks = t >> 7, kk = (t >> 6) & 1, quad = (t >> 4) & 3, col = t & 15;

    const float* src;
    __bf16* dst;
    if (g < NAGRP) {
        int row = g * 16 + col;
        src = (row < NQROWS) ? (qe + (size_t)row * D_)
                             : (de + (size_t)(row - NQROWS) * D_);
        dst = asw + (size_t)g * 4096;
    } else {
        int bit = (g - NAGRP) * 16 + col;
        src = r + (size_t)bit * D_;
        dst = rsw + (size_t)(g - NAGRP) * 4096;
    }

    const int ko = ks * 64 + kk * 32 + quad * 8;
    float4 v0 = *(const float4*)(src + ko);
    float4 v1 = *(const float4*)(src + ko + 4);
    bf16x8 hi, lo;
    hi[0] = (__bf16)v0.x; hi[1] = (__bf16)v0.y;
    hi[2] = (__bf16)v0.z; hi[3] = (__bf16)v0.w;
    hi[4] = (__bf16)v1.x; hi[5] = (__bf16)v1.y;
    hi[6] = (__bf16)v1.z; hi[7] = (__bf16)v1.w;
    lo[0] = (__bf16)(v0.x - (float)hi[0]);
    lo[1] = (__bf16)(v0.y - (float)hi[1]);
    lo[2] = (__bf16)(v0.z - (float)hi[2]);
    lo[3] = (__bf16)(v0.w - (float)hi[3]);
    lo[4] = (__bf16)(v1.x - (float)hi[4]);
    lo[5] = (__bf16)(v1.y - (float)hi[5]);
    lo[6] = (__bf16)(v1.z - (float)hi[6]);
    lo[7] = (__bf16)(v1.w - (float)hi[7]);

    const int c_hi = ks * 16 + kk * 4 + quad;   // hl=0
    const int c_lo = c_hi + 8;                  // hl=1
    *(bf16x8*)(dst + (size_t)(c_hi * 16 + col) * 8) = hi;
    *(bf16x8*)(dst + (size_t)(c_lo * 16 + col) * 8) = lo;
}

// ---- Stage 1: LSH sign-hash — pure MFMA + global fragment streaming --------
// grid (NROWS/TM=544, NBITS/TN=8), block 256 = 4 waves (2x2 of 64x64 tiles).
// No LDS, no barriers. Per (ks,kk): load ahi/bhi frags (coalesced b128 from
// swizzled global), 16 MFMA hh; load alo, 16 MFMA lh; load blo, 16 MFMA hl.
// A streamed once from HBM; B (rsw, 512 KB) is L2-resident in every XCD.
__global__ __launch_bounds__(256) void hash_kernel(
    const __bf16* __restrict__ asw, const __bf16* __restrict__ rsw,
    unsigned int* __restrict__ codes_t)
{
    const int t = threadIdx.x;
    const int wv   = t >> 6;          // wave 0..3
    const int lane = t & 63;
    const int quad = lane >> 4;       // 0..3
    const int col  = lane & 15;       // 0..15
    const int wrow = (wv >> 1) * 64;
    const int wbit = (wv & 1) * 64;
    const int ga0 = (blockIdx.x * TM + wrow) >> 4;   // A group base (+ti)
    const int gb0 = (blockIdx.y * TN + wbit) >> 4;   // B group base (+tj)

    f32x4 acc[4][4];
    #pragma unroll
    for (int ti = 0; ti < 4; ++ti)
        #pragma unroll
        for (int tj = 0; tj < 4; ++tj)
            acc[ti][tj] = (f32x4){0.f, 0.f, 0.f, 0.f};

    #pragma unroll
    for (int ks = 0; ks < 2; ++ks) {
        #pragma unroll
        for (int kk = 0; kk < 2; ++kk) {
            const int cbi_h = ks * 4 + kk;      // hl=0 chunk-quad group
            const int cbi_l = cbi_h + 2;        // hl=1
            bf16x8 ahi[4], bhi[4], alo[4], blo[4];
            #pragma unroll
            for (int ti = 0; ti < 4; ++ti)
                ahi[ti] = *(const bf16x8*)(
                    asw + (((size_t)(ga0 + ti) * 8 + cbi_h) * 64 + lane) * 8);
            #pragma unroll
            for (int tj = 0; tj < 4; ++tj)
                bhi[tj] = *(const bf16x8*)(
                    rsw + (((size_t)(gb0 + tj) * 8 + cbi_h) * 64 + lane) * 8);
            #pragma unroll
            for (int ti = 0; ti < 4; ++ti)
                #pragma unroll
                for (int tj = 0; tj < 4; ++tj)
                    acc[ti][tj] = __builtin_amdgcn_mfma_f32_16x16x32_bf16(
                        ahi[ti], bhi[tj], acc[ti][tj], 0, 0, 0);    // hi*hi
            #pragma unroll
            for (int ti = 0; ti < 4; ++ti)
                alo[ti] = *(const bf16x8*)(
                    asw + (((size_t)(ga0 + ti) * 8 + cbi_l) * 64 + lane) * 8);
            #pragma unroll
            for (int ti = 0; ti < 4; ++ti)
                #pragma unroll
                for (int tj = 0; tj < 4; ++tj)
                    acc[ti][tj] = __builtin_amdgcn_mfma_f32_16x16x32_bf16(
                        alo[ti], bhi[tj], acc[ti][tj], 0, 0, 0);    // lo*hi
            #pragma unroll
            for (int tj = 0; tj < 4; ++tj)
                blo[tj] = *(const bf16x8*)(
                    rsw + (((size_t)(gb0 + tj) * 8 + cbi_l) * 64 + lane) * 8);
            #pragma unroll
            for (int ti = 0; ti < 4; ++ti)
                #pragma unroll
                for (int tj = 0; tj < 4; ++tj)
                    acc[ti][tj] = __builtin_amdgcn_mfma_f32_16x16x32_bf16(
                        ahi[ti], blo[tj], acc[ti][tj], 0, 0, 0);    // hi*lo
        }
    }

    // Sign-pack via ballot; C/D layout (m89): col=lane&15, row=quad*4+reg.
    // TRANSPOSED store: codes_t[word][row].
    const int row0 = blockIdx.x * TM;
    #pragma unroll
    for (int ti = 0; ti < 4; ++ti) {
        #pragma unroll
        for (int rg = 0; rg < 4; ++rg) {
            unsigned long long b[4];
            #pragma unroll
            for (int tj = 0; tj < 4; ++tj)
                b[tj] = __ballot(acc[ti][tj][rg] > 0.f);
            if (col < 2) {
                const int w = col;
                unsigned int lo16 = (unsigned int)(b[2 * w]     >> (16 * quad)) & 0xFFFFu;
                unsigned int hi16 = (unsigned int)(b[2 * w + 1] >> (16 * quad)) & 0xFFFFu;
                const int row = row0 + wrow + ti * 16 + quad * 4 + rg;
                const int wg  = blockIdx.y * 4 + (wv & 1) * 2 + w;
                codes_t[(size_t)wg * NROWS + row] = lo16 | (hi16 << 16);
            }
        }
    }
}

// ---- Stage 2: Hamming -> cos (HW v_cos) -> mask -> out ---------------------
// UNCHANGED from R9. grid: 2048 blocks, 8 blocks/CU.
__global__ __launch_bounds__(256) void simmat_kernel(
    const unsigned int* __restrict__ codes_t,
    const int* __restrict__ qtok, const int* __restrict__ dtok,
    float* __restrict__ out)
{
    __shared__ unsigned int qc[8 * 36];

    const int blk  = blockIdx.x;
    const int ct   = blk & 3;
    const int asub = (blk >> 2) & 7;
    const int b    = (blk >> 5) & 31;
    const int l    = blk >> 10;
    const int t    = threadIdx.x;

    const int a0 = asub * 8;
    const int qrow0 = (l * BAT_ + b) * A_ + a0;
    if (t < 256) {
        int w = t >> 3, a = t & 7;
        qc[a * 36 + w] = codes_t[(size_t)w * NROWS + qrow0 + a];
    }
    __syncthreads();

    const int c = ct * 256 + t;
    const size_t drow = (size_t)NQROWS + (size_t)(l * BAT_ + b) * B_ + c;
    unsigned int dc[NW];
    #pragma unroll
    for (int w = 0; w < NW; ++w) dc[w] = codes_t[(size_t)w * NROWS + drow];
    const float dm = (dtok[b * B_ + c] != 0) ? 1.f : 0.f;

    float* obase = out + ((size_t)((b * L_ + l) * A_ + a0)) * B_ + c;
    #pragma unroll
    for (int ai = 0; ai < 8; ++ai) {
        int ham = 0;
        #pragma unroll
        for (int m = 0; m < 8; ++m) {
            uint4 qv = *(const uint4*)(&qc[ai * 36 + m * 4]);
            ham += __popc(qv.x ^ dc[4 * m])     + __popc(qv.y ^ dc[4 * m + 1])
                 + __popc(qv.z ^ dc[4 * m + 2]) + __popc(qv.w ^ dc[4 * m + 3]);
        }
        const float qmv = (qtok[b * A_ + a0 + ai] != 0) ? 1.f : 0.f;
        float sim = __cosf((float)M_PI / (float)NBITS_ * (float)ham);
        obase[(size_t)ai * B_] = sim * (qmv * dm);
    }
}

extern "C" void kernel_launch(void* const* d_in, const int* in_sizes, int n_in,
                              void* d_out, int out_size, void* d_ws, size_t ws_size,
                              hipStream_t stream) {
    const float* qe  = (const float*)d_in[0];  // [L,BAT,A,D]
    const float* de  = (const float*)d_in[1];  // [L,BAT,B,D]
    const int* qtok  = (const int*)d_in[2];    // [BAT,A]
    const int* dtok  = (const int*)d_in[3];    // [BAT,B]
    const float* r   = (const float*)d_in[4];  // [NBITS,D]
    float* out = (float*)d_out;                // [BAT,L,A,B] fp32

    // ws: [0, 8.5MB) codes_t | [8.5, 9.0MB) rsw | [9.0MB, +34MB) asw
    unsigned int* codes_t = (unsigned int*)d_ws;                    // 8912896 B
    __bf16* rsw = (__bf16*)((char*)d_ws + 8912896);                 // 524288 B
    __bf16* asw = (__bf16*)((char*)d_ws + 8912896 + 524288);        // 35651584 B

    preswz_kernel<<<NAGRP + NBGRP, 256, 0, stream>>>(qe, de, r, asw, rsw);
    dim3 g1(NROWS / TM, NBITS_ / TN);
    hash_kernel<<<g1, 256, 0, stream>>>(asw, rsw, codes_t);
    simmat_kernel<<<L_ * BAT_ * 8 * 4, 256, 0, stream>>>(codes_t, qtok, dtok, out);
}